// Round 1
// baseline (1523.873 us; speedup 1.0000x reference)
//
#include <hip/hip_runtime.h>
#include <math.h>
#include <cstddef>

#define NN 100000
#define NE 1600000
#define CH 256
#define OC 40

// ---------------- graph build ----------------

__global__ void hist_kernel(const int* __restrict__ dst, int* __restrict__ deg, int E) {
    int i = blockIdx.x * blockDim.x + threadIdx.x;
    int st = gridDim.x * blockDim.x;
    for (; i < E; i += st) atomicAdd(&deg[dst[i]], 1);
}

__global__ void dinv_kernel(const int* __restrict__ deg, float* __restrict__ dinv, int n) {
    int i = blockIdx.x * blockDim.x + threadIdx.x;
    if (i < n) dinv[i] = rsqrtf((float)deg[i] + 1.0f);
}

// single-block scan: row_ptr = exclusive_scan(deg+1), row width includes self-loop
__global__ __launch_bounds__(1024) void scan_kernel(const int* __restrict__ deg,
                                                    int* __restrict__ row_ptr, int n) {
    __shared__ int sums[1024];
    int t = threadIdx.x;
    int chunk = (n + 1023) >> 10;
    int s0 = t * chunk;
    int s1 = s0 + chunk; if (s1 > n) s1 = n;
    int s = 0;
    for (int i = s0; i < s1; ++i) s += deg[i] + 1;
    sums[t] = s;
    __syncthreads();
    for (int off = 1; off < 1024; off <<= 1) {
        int v = (t >= off) ? sums[t - off] : 0;
        __syncthreads();
        sums[t] += v;
        __syncthreads();
    }
    int run = (t == 0) ? 0 : sums[t - 1];
    for (int i = s0; i < s1; ++i) { row_ptr[i] = run; run += deg[i] + 1; }
    if (t == 0) row_ptr[n] = sums[1023];
}

// scatter edges into CSR; last slot of each row = self loop (norm = dinv^2)
__global__ void fill_kernel(const int* __restrict__ src, const int* __restrict__ dst,
                            const int* __restrict__ row_ptr, int* __restrict__ cursor,
                            const float* __restrict__ dinv,
                            int* __restrict__ csr_src, float* __restrict__ csr_norm,
                            int E, int n) {
    int i = blockIdx.x * blockDim.x + threadIdx.x;
    int st = gridDim.x * blockDim.x;
    int total = E + n;
    for (; i < total; i += st) {
        if (i < E) {
            int s = src[i], d = dst[i];
            int pos = row_ptr[d] + atomicAdd(&cursor[d], 1);
            csr_src[pos] = s;
            csr_norm[pos] = dinv[s] * dinv[d];
        } else {
            int v = i - E;
            int pos = row_ptr[v + 1] - 1;
            csr_src[pos] = v;
            csr_norm[pos] = dinv[v] * dinv[v];
        }
    }
}

// ---------------- GEMM: C[M x 256] = A[M x 256] @ W[256 x 256] ----------------
// 256 threads, BM=64, BN=256, BK=32, 8x8 register blocking per thread.
__global__ __launch_bounds__(256) void gemm256_kernel(const float* __restrict__ A,
                                                      const float* __restrict__ W,
                                                      float* __restrict__ C, int M) {
    __shared__ float Xs[64][36];   // pad 36: 16B-aligned stores + conflict-free col reads
    __shared__ float Ws[32][256];
    const int t = threadIdx.x;
    const int tr = t >> 5;         // 0..7
    const int tc = t & 31;         // 0..31
    const int row0 = blockIdx.x * 64;

    float acc[8][8];
    #pragma unroll
    for (int i = 0; i < 8; i++) {
        #pragma unroll
        for (int j = 0; j < 8; j++) acc[i][j] = 0.f;
    }

    const int xra = t >> 3;          // 0..31
    const int xcc = (t & 7) << 2;    // 0..28
    const int wcol = (t & 63) << 2;  // 0..252
    const int wrb = t >> 6;          // 0..3

    for (int k0 = 0; k0 < 256; k0 += 32) {
        #pragma unroll
        for (int p = 0; p < 2; p++) {
            int r = xra + p * 32;
            int gr = row0 + r;
            float4 v = make_float4(0.f, 0.f, 0.f, 0.f);
            if (gr < M) v = *reinterpret_cast<const float4*>(A + (size_t)gr * 256 + k0 + xcc);
            *reinterpret_cast<float4*>(&Xs[r][xcc]) = v;
        }
        #pragma unroll
        for (int p = 0; p < 8; p++) {
            int r = wrb + p * 4;
            *reinterpret_cast<float4*>(&Ws[r][wcol]) =
                *reinterpret_cast<const float4*>(W + (size_t)(k0 + r) * 256 + wcol);
        }
        __syncthreads();
        #pragma unroll 8
        for (int kk = 0; kk < 32; ++kk) {
            float a[8], b[8];
            #pragma unroll
            for (int i = 0; i < 8; i++) a[i] = Xs[tr * 8 + i][kk];
            *reinterpret_cast<float4*>(&b[0]) = *reinterpret_cast<float4*>(&Ws[kk][tc * 4]);
            *reinterpret_cast<float4*>(&b[4]) = *reinterpret_cast<float4*>(&Ws[kk][128 + tc * 4]);
            #pragma unroll
            for (int i = 0; i < 8; i++) {
                #pragma unroll
                for (int j = 0; j < 8; j++) acc[i][j] = fmaf(a[i], b[j], acc[i][j]);
            }
        }
        __syncthreads();
    }
    #pragma unroll
    for (int i = 0; i < 8; i++) {
        int gr = row0 + tr * 8 + i;
        if (gr < M) {
            float4 v0 = make_float4(acc[i][0], acc[i][1], acc[i][2], acc[i][3]);
            float4 v1 = make_float4(acc[i][4], acc[i][5], acc[i][6], acc[i][7]);
            *reinterpret_cast<float4*>(C + (size_t)gr * 256 + tc * 4) = v0;
            *reinterpret_cast<float4*>(C + (size_t)gr * 256 + 128 + tc * 4) = v1;
        }
    }
}

// ---------------- GEMM: C[M x 40] = A[M x 256] @ W[256 x 40] ----------------
// 256 threads, BM=128, BK=64; thread = (row, 20-col group)
__global__ __launch_bounds__(256) void gemm40_kernel(const float* __restrict__ A,
                                                     const float* __restrict__ W,
                                                     float* __restrict__ C, int M) {
    __shared__ float Hs[128][65];
    __shared__ float Ws[64][40];
    const int t = threadIdx.x;
    const int tr = t & 127;
    const int tg = t >> 7;   // 0..1
    const int row0 = blockIdx.x * 128;
    float acc[20];
    #pragma unroll
    for (int j = 0; j < 20; j++) acc[j] = 0.f;

    const int hr = t >> 4;          // 0..15
    const int hc = (t & 15) << 2;   // 0..60

    for (int k0 = 0; k0 < 256; k0 += 64) {
        #pragma unroll
        for (int p = 0; p < 8; p++) {
            int r = hr + p * 16;
            int gr = row0 + r;
            float4 v = make_float4(0.f, 0.f, 0.f, 0.f);
            if (gr < M) v = *reinterpret_cast<const float4*>(A + (size_t)gr * 256 + k0 + hc);
            Hs[r][hc] = v.x; Hs[r][hc + 1] = v.y; Hs[r][hc + 2] = v.z; Hs[r][hc + 3] = v.w;
        }
        for (int i = t; i < 64 * 40; i += 256) {
            int r = i / 40, c = i - r * 40;
            Ws[r][c] = W[(size_t)(k0 + r) * 40 + c];
        }
        __syncthreads();
        #pragma unroll 4
        for (int kk = 0; kk < 64; ++kk) {
            float a = Hs[tr][kk];
            float b[20];
            #pragma unroll
            for (int q = 0; q < 5; q++)
                *reinterpret_cast<float4*>(&b[q * 4]) =
                    *reinterpret_cast<float4*>(&Ws[kk][tg * 20 + q * 4]);
            #pragma unroll
            for (int j = 0; j < 20; j++) acc[j] = fmaf(a, b[j], acc[j]);
        }
        __syncthreads();
    }
    int gr = row0 + tr;
    if (gr < M) {
        #pragma unroll
        for (int q = 0; q < 5; q++) {
            float4 v = make_float4(acc[q * 4], acc[q * 4 + 1], acc[q * 4 + 2], acc[q * 4 + 3]);
            *reinterpret_cast<float4*>(C + (size_t)gr * 40 + tg * 20 + q * 4) = v;
        }
    }
}

// ---------------- aggregation: H[i] = sum_e norm_e * T[src_e] + b (+relu) ----------------
// one wave per node; 64 lanes x float4 = 1KB row per gather
__global__ __launch_bounds__(256) void agg256_kernel(const float* __restrict__ T,
        const int* __restrict__ row_ptr, const int* __restrict__ csr_src,
        const float* __restrict__ csr_norm, const float* __restrict__ bias,
        float* __restrict__ H, int n, int do_relu) {
    int wid = threadIdx.x >> 6, lane = threadIdx.x & 63;
    int node = blockIdx.x * 4 + wid;
    if (node >= n) return;
    int e = row_ptr[node], end = row_ptr[node + 1];
    float4 acc = make_float4(0.f, 0.f, 0.f, 0.f);
    for (; e + 1 < end; e += 2) {
        int s0 = csr_src[e], s1 = csr_src[e + 1];
        float w0 = csr_norm[e], w1 = csr_norm[e + 1];
        float4 v0 = *(reinterpret_cast<const float4*>(T + (size_t)s0 * 256) + lane);
        float4 v1 = *(reinterpret_cast<const float4*>(T + (size_t)s1 * 256) + lane);
        acc.x = fmaf(w0, v0.x, acc.x); acc.y = fmaf(w0, v0.y, acc.y);
        acc.z = fmaf(w0, v0.z, acc.z); acc.w = fmaf(w0, v0.w, acc.w);
        acc.x = fmaf(w1, v1.x, acc.x); acc.y = fmaf(w1, v1.y, acc.y);
        acc.z = fmaf(w1, v1.z, acc.z); acc.w = fmaf(w1, v1.w, acc.w);
    }
    if (e < end) {
        int s0 = csr_src[e];
        float w0 = csr_norm[e];
        float4 v0 = *(reinterpret_cast<const float4*>(T + (size_t)s0 * 256) + lane);
        acc.x = fmaf(w0, v0.x, acc.x); acc.y = fmaf(w0, v0.y, acc.y);
        acc.z = fmaf(w0, v0.z, acc.z); acc.w = fmaf(w0, v0.w, acc.w);
    }
    float4 bb = *(reinterpret_cast<const float4*>(bias) + lane);
    acc.x += bb.x; acc.y += bb.y; acc.z += bb.z; acc.w += bb.w;
    if (do_relu) {
        acc.x = fmaxf(acc.x, 0.f); acc.y = fmaxf(acc.y, 0.f);
        acc.z = fmaxf(acc.z, 0.f); acc.w = fmaxf(acc.w, 0.f);
    }
    *(reinterpret_cast<float4*>(H + (size_t)node * 256) + lane) = acc;
}

// final layer: 40-channel aggregation + bias + log_softmax fused
__global__ __launch_bounds__(256) void agg40_kernel(const float* __restrict__ T3,
        const int* __restrict__ row_ptr, const int* __restrict__ csr_src,
        const float* __restrict__ csr_norm, const float* __restrict__ bias,
        float* __restrict__ Out, int n) {
    int wid = threadIdx.x >> 6, lane = threadIdx.x & 63;
    int node = blockIdx.x * 4 + wid;
    if (node >= n) return;
    bool act = lane < OC;
    int e = row_ptr[node], end = row_ptr[node + 1];
    float acc = 0.f;
    for (; e < end; ++e) {
        int s = csr_src[e];
        float w = csr_norm[e];
        float v = act ? T3[(size_t)s * OC + lane] : 0.f;
        acc = fmaf(w, v, acc);
    }
    float bb = act ? bias[lane] : 0.f;
    float x = act ? (acc + bb) : -INFINITY;
    float m = x;
    #pragma unroll
    for (int off = 32; off; off >>= 1) m = fmaxf(m, __shfl_xor(m, off));
    float ex = act ? expf(x - m) : 0.f;
    float ssum = ex;
    #pragma unroll
    for (int off = 32; off; off >>= 1) ssum += __shfl_xor(ssum, off);
    if (act) Out[(size_t)node * OC + lane] = x - m - logf(ssum);
}

// ---------------- launch ----------------

extern "C" void kernel_launch(void* const* d_in, const int* in_sizes, int n_in,
                              void* d_out, int out_size, void* d_ws, size_t ws_size,
                              hipStream_t stream) {
    const float* x  = (const float*)d_in[0];
    const int* ei   = (const int*)d_in[1];
    const int* esrc = ei;
    const int* edst = ei + NE;
    const float* W1 = (const float*)d_in[2];
    const float* b1 = (const float*)d_in[3];
    const float* W2 = (const float*)d_in[4];
    const float* b2 = (const float*)d_in[5];
    const float* W3 = (const float*)d_in[6];
    const float* b3 = (const float*)d_in[7];
    float* out = (float*)d_out;

    char* p = (char*)d_ws;
    int* deg      = (int*)p;   p += 400000;              // [NN]
    int* cursor   = (int*)p;   p += 400000;              // [NN] (contiguous w/ deg for one memset)
    int* row_ptr  = (int*)p;   p += 400128;              // [NN+1]
    float* dinv   = (float*)p; p += 400000;              // [NN]
    int* csr_src  = (int*)p;   p += (size_t)(NE + NN) * 4;
    float* csr_nm = (float*)p; p += (size_t)(NE + NN) * 4;
    float* T      = (float*)p; p += (size_t)NN * CH * 4; // XW buffer
    float* H      = (float*)p; p += (size_t)NN * CH * 4; // post-agg buffer

    hipMemsetAsync(deg, 0, 800000, stream);  // deg + cursor

    hist_kernel<<<2048, 256, 0, stream>>>(edst, deg, NE);
    dinv_kernel<<<(NN + 255) / 256, 256, 0, stream>>>(deg, dinv, NN);
    scan_kernel<<<1, 1024, 0, stream>>>(deg, row_ptr, NN);
    fill_kernel<<<2048, 256, 0, stream>>>(esrc, edst, row_ptr, cursor, dinv,
                                          csr_src, csr_nm, NE, NN);

    // layer 1
    gemm256_kernel<<<(NN + 63) / 64, 256, 0, stream>>>(x, W1, T, NN);
    agg256_kernel<<<NN / 4, 256, 0, stream>>>(T, row_ptr, csr_src, csr_nm, b1, H, NN, 1);
    // layer 2
    gemm256_kernel<<<(NN + 63) / 64, 256, 0, stream>>>(H, W2, T, NN);
    agg256_kernel<<<NN / 4, 256, 0, stream>>>(T, row_ptr, csr_src, csr_nm, b2, H, NN, 1);
    // layer 3 + log_softmax
    gemm40_kernel<<<(NN + 127) / 128, 256, 0, stream>>>(H, W3, T, NN);
    agg40_kernel<<<NN / 4, 256, 0, stream>>>(T, row_ptr, csr_src, csr_nm, b3, out, NN);
}

// Round 2
// 1080.870 us; speedup vs baseline: 1.4099x; 1.4099x over previous
//
#include <hip/hip_runtime.h>
#include <math.h>
#include <cstddef>

#define NN 100000
#define NE 1600000
#define CH 256
#define OC 40

typedef __attribute__((ext_vector_type(8))) short bf16x8;
typedef __attribute__((ext_vector_type(4))) float f32x4;

static __device__ __forceinline__ unsigned short f2bf(float f) {
    unsigned int u = __float_as_uint(f);
    unsigned int r = (u + 0x7FFFu + ((u >> 16) & 1u)) >> 16;
    return (unsigned short)r;
}
static __device__ __forceinline__ float bflo(unsigned int u) {  // low bf16 of packed word
    return __uint_as_float(u << 16);
}
static __device__ __forceinline__ float bfhi(unsigned int u) {  // high bf16
    return __uint_as_float(u & 0xFFFF0000u);
}

// ---------------- graph build ----------------

__global__ void hist_kernel(const int* __restrict__ dst, int* __restrict__ deg, int E) {
    int i = blockIdx.x * blockDim.x + threadIdx.x;
    int st = gridDim.x * blockDim.x;
    for (; i < E; i += st) atomicAdd(&deg[dst[i]], 1);
}

__global__ void dinv_kernel(const int* __restrict__ deg, float* __restrict__ dinv, int n) {
    int i = blockIdx.x * blockDim.x + threadIdx.x;
    if (i < n) dinv[i] = rsqrtf((float)deg[i] + 1.0f);
}

__global__ __launch_bounds__(1024) void scan_kernel(const int* __restrict__ deg,
                                                    int* __restrict__ row_ptr, int n) {
    __shared__ int sums[1024];
    int t = threadIdx.x;
    int chunk = (n + 1023) >> 10;
    int s0 = t * chunk;
    int s1 = s0 + chunk; if (s1 > n) s1 = n;
    int s = 0;
    for (int i = s0; i < s1; ++i) s += deg[i] + 1;
    sums[t] = s;
    __syncthreads();
    for (int off = 1; off < 1024; off <<= 1) {
        int v = (t >= off) ? sums[t - off] : 0;
        __syncthreads();
        sums[t] += v;
        __syncthreads();
    }
    int run = (t == 0) ? 0 : sums[t - 1];
    for (int i = s0; i < s1; ++i) { row_ptr[i] = run; run += deg[i] + 1; }
    if (t == 0) row_ptr[n] = sums[1023];
}

__global__ void fill_kernel(const int* __restrict__ src, const int* __restrict__ dst,
                            const int* __restrict__ row_ptr, int* __restrict__ cursor,
                            const float* __restrict__ dinv,
                            int* __restrict__ csr_src, float* __restrict__ csr_norm,
                            int E, int n) {
    int i = blockIdx.x * blockDim.x + threadIdx.x;
    int st = gridDim.x * blockDim.x;
    int total = E + n;
    for (; i < total; i += st) {
        if (i < E) {
            int s = src[i], d = dst[i];
            int pos = row_ptr[d] + atomicAdd(&cursor[d], 1);
            csr_src[pos] = s;
            csr_norm[pos] = dinv[s] * dinv[d];
        } else {
            int v = i - E;
            int pos = row_ptr[v + 1] - 1;
            csr_src[pos] = v;
            csr_norm[pos] = dinv[v] * dinv[v];
        }
    }
}

// ---------------- prep: f32 -> bf16 conversions ----------------

__global__ void f2b8_kernel(const float* __restrict__ in, unsigned short* __restrict__ out,
                            int ngroups) {
    int i = blockIdx.x * blockDim.x + threadIdx.x;
    if (i >= ngroups) return;
    float4 a = reinterpret_cast<const float4*>(in)[(size_t)i * 2];
    float4 b = reinterpret_cast<const float4*>(in)[(size_t)i * 2 + 1];
    uint4 r;
    r.x = f2bf(a.x) | ((unsigned)f2bf(a.y) << 16);
    r.y = f2bf(a.z) | ((unsigned)f2bf(a.w) << 16);
    r.z = f2bf(b.x) | ((unsigned)f2bf(b.y) << 16);
    r.w = f2bf(b.z) | ((unsigned)f2bf(b.w) << 16);
    reinterpret_cast<uint4*>(out)[i] = r;
}

// Wt[n][k] = bf16(W[k][n]); K=N=256
__global__ void wtrans_kernel(const float* __restrict__ W, unsigned short* __restrict__ Wt) {
    __shared__ float tile[16][17];
    int k = blockIdx.y * 16 + threadIdx.y;
    int n = blockIdx.x * 16 + threadIdx.x;
    tile[threadIdx.y][threadIdx.x] = W[(size_t)k * 256 + n];
    __syncthreads();
    int on = blockIdx.x * 16 + threadIdx.y;
    int ok = blockIdx.y * 16 + threadIdx.x;
    Wt[(size_t)on * 256 + ok] = f2bf(tile[threadIdx.x][threadIdx.y]);
}

// ---------------- bf16 MFMA GEMM: C[M x 256] = A[M x 256] @ Wt^T ----------------
// A row-major bf16, Wt[n][k] bf16 (pre-transposed). BM=128, BN=128, BK=32.
// 4 waves, each owns a 64x64 sub-tile = 4x4 fragments of 16x16x32 MFMA.
__global__ __launch_bounds__(256) void gemm_bf16_kernel(
        const unsigned short* __restrict__ A, const unsigned short* __restrict__ Wt,
        unsigned short* __restrict__ C, int M) {
    __shared__ __align__(16) unsigned short As[128 * 40];  // stride 40 (80B): 16B-aligned + conflict-free
    __shared__ __align__(16) unsigned short Bs[128 * 40];
    const int t = threadIdx.x;
    const int l = t & 63;
    const int w = t >> 6;
    const int wr = w >> 1, wc = w & 1;
    const int row0 = blockIdx.x * 128;
    const int col0 = blockIdx.y * 128;

    f32x4 acc[4][4];
    #pragma unroll
    for (int m = 0; m < 4; m++)
        #pragma unroll
        for (int n = 0; n < 4; n++) acc[m][n] = (f32x4){0.f, 0.f, 0.f, 0.f};

    const int sr = t >> 2;           // staging row 0..63
    const int sc = (t & 3) * 8;      // k-chunk 0,8,16,24

    const int rl = l & 15;           // fragment row/col within 16
    const int kb = (l >> 4) * 8;     // fragment k-offset

    for (int k0 = 0; k0 < 256; k0 += 32) {
        #pragma unroll
        for (int p = 0; p < 2; p++) {
            int r = sr + p * 64;
            int gr = row0 + r;
            uint4 v = make_uint4(0u, 0u, 0u, 0u);
            if (gr < M) v = *reinterpret_cast<const uint4*>(A + (size_t)gr * 256 + k0 + sc);
            *reinterpret_cast<uint4*>(&As[r * 40 + sc]) = v;
            uint4 u = *reinterpret_cast<const uint4*>(Wt + (size_t)(col0 + r) * 256 + k0 + sc);
            *reinterpret_cast<uint4*>(&Bs[r * 40 + sc]) = u;
        }
        __syncthreads();
        bf16x8 af[4], bfr[4];
        #pragma unroll
        for (int m = 0; m < 4; m++)
            af[m] = *reinterpret_cast<const bf16x8*>(&As[(wr * 64 + m * 16 + rl) * 40 + kb]);
        #pragma unroll
        for (int n = 0; n < 4; n++)
            bfr[n] = *reinterpret_cast<const bf16x8*>(&Bs[(wc * 64 + n * 16 + rl) * 40 + kb]);
        #pragma unroll
        for (int m = 0; m < 4; m++)
            #pragma unroll
            for (int n = 0; n < 4; n++)
                acc[m][n] = __builtin_amdgcn_mfma_f32_16x16x32_bf16(af[m], bfr[n], acc[m][n], 0, 0, 0);
        __syncthreads();
    }
    // C/D layout: col = lane&15, row = (lane>>4)*4 + reg   [m89-verified]
    const int rh = l >> 4;
    #pragma unroll
    for (int m = 0; m < 4; m++) {
        #pragma unroll
        for (int n = 0; n < 4; n++) {
            #pragma unroll
            for (int j = 0; j < 4; j++) {
                int gr = row0 + wr * 64 + m * 16 + rh * 4 + j;
                int gc = col0 + wc * 64 + n * 16 + rl;
                if (gr < M) C[(size_t)gr * 256 + gc] = f2bf(acc[m][n][j]);
            }
        }
    }
}

// ---------------- GEMM: T3[M x 40] = Hb[M x 256](bf16) @ W3[256 x 40](f32) ----------------
__global__ __launch_bounds__(256) void gemm40_kernel(const unsigned short* __restrict__ A,
                                                     const float* __restrict__ W,
                                                     float* __restrict__ C, int M) {
    __shared__ float Hs[128][65];
    __shared__ float Ws[64][40];
    const int t = threadIdx.x;
    const int tr = t & 127;
    const int tg = t >> 7;
    const int row0 = blockIdx.x * 128;
    float acc[20];
    #pragma unroll
    for (int j = 0; j < 20; j++) acc[j] = 0.f;

    const int hr = t >> 4;
    const int hc = (t & 15) << 2;

    for (int k0 = 0; k0 < 256; k0 += 64) {
        #pragma unroll
        for (int p = 0; p < 8; p++) {
            int r = hr + p * 16;
            int gr = row0 + r;
            uint2 u = make_uint2(0u, 0u);
            if (gr < M) u = *reinterpret_cast<const uint2*>(A + (size_t)gr * 256 + k0 + hc);
            Hs[r][hc] = bflo(u.x); Hs[r][hc + 1] = bfhi(u.x);
            Hs[r][hc + 2] = bflo(u.y); Hs[r][hc + 3] = bfhi(u.y);
        }
        for (int i = t; i < 64 * 40; i += 256) {
            int r = i / 40, c = i - r * 40;
            Ws[r][c] = W[(size_t)(k0 + r) * 40 + c];
        }
        __syncthreads();
        #pragma unroll 4
        for (int kk = 0; kk < 64; ++kk) {
            float a = Hs[tr][kk];
            float b[20];
            #pragma unroll
            for (int q = 0; q < 5; q++)
                *reinterpret_cast<float4*>(&b[q * 4]) =
                    *reinterpret_cast<float4*>(&Ws[kk][tg * 20 + q * 4]);
            #pragma unroll
            for (int j = 0; j < 20; j++) acc[j] = fmaf(a, b[j], acc[j]);
        }
        __syncthreads();
    }
    int gr = row0 + tr;
    if (gr < M) {
        #pragma unroll
        for (int q = 0; q < 5; q++) {
            float4 v = make_float4(acc[q * 4], acc[q * 4 + 1], acc[q * 4 + 2], acc[q * 4 + 3]);
            *reinterpret_cast<float4*>(C + (size_t)gr * 40 + tg * 20 + q * 4) = v;
        }
    }
}

// ---------------- aggregation (bf16 in / bf16 out, f32 accum) ----------------
// one wave per node; lane handles 4 channels (8B gathers)
__global__ __launch_bounds__(256) void aggb_kernel(const unsigned short* __restrict__ T,
        const int* __restrict__ row_ptr, const int* __restrict__ csr_src,
        const float* __restrict__ csr_norm, const float* __restrict__ bias,
        unsigned short* __restrict__ H, int n, int do_relu) {
    int wid = threadIdx.x >> 6, lane = threadIdx.x & 63;
    int node = blockIdx.x * 4 + wid;
    if (node >= n) return;
    int e = row_ptr[node], end = row_ptr[node + 1];
    float a0 = 0.f, a1 = 0.f, a2 = 0.f, a3 = 0.f;
    for (; e + 1 < end; e += 2) {
        int s0 = csr_src[e], s1 = csr_src[e + 1];
        float w0 = csr_norm[e], w1 = csr_norm[e + 1];
        uint2 u0 = *reinterpret_cast<const uint2*>(T + (size_t)s0 * 256 + lane * 4);
        uint2 u1 = *reinterpret_cast<const uint2*>(T + (size_t)s1 * 256 + lane * 4);
        a0 = fmaf(w0, bflo(u0.x), a0); a1 = fmaf(w0, bfhi(u0.x), a1);
        a2 = fmaf(w0, bflo(u0.y), a2); a3 = fmaf(w0, bfhi(u0.y), a3);
        a0 = fmaf(w1, bflo(u1.x), a0); a1 = fmaf(w1, bfhi(u1.x), a1);
        a2 = fmaf(w1, bflo(u1.y), a2); a3 = fmaf(w1, bfhi(u1.y), a3);
    }
    if (e < end) {
        int s0 = csr_src[e];
        float w0 = csr_norm[e];
        uint2 u0 = *reinterpret_cast<const uint2*>(T + (size_t)s0 * 256 + lane * 4);
        a0 = fmaf(w0, bflo(u0.x), a0); a1 = fmaf(w0, bfhi(u0.x), a1);
        a2 = fmaf(w0, bflo(u0.y), a2); a3 = fmaf(w0, bfhi(u0.y), a3);
    }
    float4 bb = reinterpret_cast<const float4*>(bias)[lane];
    a0 += bb.x; a1 += bb.y; a2 += bb.z; a3 += bb.w;
    if (do_relu) {
        a0 = fmaxf(a0, 0.f); a1 = fmaxf(a1, 0.f);
        a2 = fmaxf(a2, 0.f); a3 = fmaxf(a3, 0.f);
    }
    uint2 o;
    o.x = f2bf(a0) | ((unsigned)f2bf(a1) << 16);
    o.y = f2bf(a2) | ((unsigned)f2bf(a3) << 16);
    *reinterpret_cast<uint2*>(H + (size_t)node * 256 + lane * 4) = o;
}

// final layer: 40-channel aggregation + bias + log_softmax fused (all f32)
__global__ __launch_bounds__(256) void agg40_kernel(const float* __restrict__ T3,
        const int* __restrict__ row_ptr, const int* __restrict__ csr_src,
        const float* __restrict__ csr_norm, const float* __restrict__ bias,
        float* __restrict__ Out, int n) {
    int wid = threadIdx.x >> 6, lane = threadIdx.x & 63;
    int node = blockIdx.x * 4 + wid;
    if (node >= n) return;
    bool act = lane < OC;
    int e = row_ptr[node], end = row_ptr[node + 1];
    float acc = 0.f;
    for (; e < end; ++e) {
        int s = csr_src[e];
        float w = csr_norm[e];
        float v = act ? T3[(size_t)s * OC + lane] : 0.f;
        acc = fmaf(w, v, acc);
    }
    float bb = act ? bias[lane] : 0.f;
    float x = act ? (acc + bb) : -INFINITY;
    float m = x;
    #pragma unroll
    for (int off = 32; off; off >>= 1) m = fmaxf(m, __shfl_xor(m, off));
    float ex = act ? expf(x - m) : 0.f;
    float ssum = ex;
    #pragma unroll
    for (int off = 32; off; off >>= 1) ssum += __shfl_xor(ssum, off);
    if (act) Out[(size_t)node * OC + lane] = x - m - logf(ssum);
}

// ---------------- launch ----------------

extern "C" void kernel_launch(void* const* d_in, const int* in_sizes, int n_in,
                              void* d_out, int out_size, void* d_ws, size_t ws_size,
                              hipStream_t stream) {
    const float* x  = (const float*)d_in[0];
    const int* ei   = (const int*)d_in[1];
    const int* esrc = ei;
    const int* edst = ei + NE;
    const float* W1 = (const float*)d_in[2];
    const float* b1 = (const float*)d_in[3];
    const float* W2 = (const float*)d_in[4];
    const float* b2 = (const float*)d_in[5];
    const float* W3 = (const float*)d_in[6];
    const float* b3 = (const float*)d_in[7];
    float* out = (float*)d_out;

    char* p = (char*)d_ws;
    int* deg      = (int*)p;   p += 400000;
    int* cursor   = (int*)p;   p += 400000;
    int* row_ptr  = (int*)p;   p += 400128;
    float* dinv   = (float*)p; p += 400000;
    int* csr_src  = (int*)p;   p += (size_t)(NE + NN) * 4;
    float* csr_nm = (float*)p; p += (size_t)(NE + NN) * 4;
    unsigned short* Xb  = (unsigned short*)p; p += (size_t)NN * CH * 2;
    unsigned short* Wt1 = (unsigned short*)p; p += 256 * 256 * 2;
    unsigned short* Wt2 = (unsigned short*)p; p += 256 * 256 * 2;
    unsigned short* Tb  = (unsigned short*)p; p += (size_t)NN * CH * 2;
    unsigned short* Hb  = (unsigned short*)p; p += (size_t)NN * CH * 2;
    float* T3     = (float*)p; p += (size_t)NN * OC * 4;

    hipMemsetAsync(deg, 0, 800000, stream);  // deg + cursor

    // graph build
    hist_kernel<<<2048, 256, 0, stream>>>(edst, deg, NE);
    dinv_kernel<<<(NN + 255) / 256, 256, 0, stream>>>(deg, dinv, NN);
    scan_kernel<<<1, 1024, 0, stream>>>(deg, row_ptr, NN);
    fill_kernel<<<2048, 256, 0, stream>>>(esrc, edst, row_ptr, cursor, dinv,
                                          csr_src, csr_nm, NE, NN);

    // prep conversions
    f2b8_kernel<<<(NN * CH / 8 + 255) / 256, 256, 0, stream>>>(x, Xb, NN * CH / 8);
    {
        dim3 g(16, 16), b(16, 16);
        wtrans_kernel<<<g, b, 0, stream>>>(W1, Wt1);
        wtrans_kernel<<<g, b, 0, stream>>>(W2, Wt2);
    }

    dim3 gg((NN + 127) / 128, 2);
    // layer 1
    gemm_bf16_kernel<<<gg, 256, 0, stream>>>(Xb, Wt1, Tb, NN);
    aggb_kernel<<<NN / 4, 256, 0, stream>>>(Tb, row_ptr, csr_src, csr_nm, b1, Hb, NN, 1);
    // layer 2
    gemm_bf16_kernel<<<gg, 256, 0, stream>>>(Hb, Wt2, Tb, NN);
    aggb_kernel<<<NN / 4, 256, 0, stream>>>(Tb, row_ptr, csr_src, csr_nm, b2, Hb, NN, 1);
    // layer 3 (f32 path) + log_softmax
    gemm40_kernel<<<(NN + 127) / 128, 256, 0, stream>>>(Hb, W3, T3, NN);
    agg40_kernel<<<NN / 4, 256, 0, stream>>>(T3, row_ptr, csr_src, csr_nm, b3, out, NN);
}

// Round 3
// 1007.169 us; speedup vs baseline: 1.5130x; 1.0732x over previous
//
#include <hip/hip_runtime.h>
#include <math.h>
#include <cstddef>

#define NN 100000
#define NE 1600000
#define CH 256
#define OC 40

typedef __attribute__((ext_vector_type(8))) short bf16x8;
typedef __attribute__((ext_vector_type(4))) float f32x4;

static __device__ __forceinline__ unsigned short f2bf(float f) {
    unsigned int u = __float_as_uint(f);
    unsigned int r = (u + 0x7FFFu + ((u >> 16) & 1u)) >> 16;
    return (unsigned short)r;
}
static __device__ __forceinline__ float bflo(unsigned int u) {
    return __uint_as_float(u << 16);
}
static __device__ __forceinline__ float bfhi(unsigned int u) {
    return __uint_as_float(u & 0xFFFF0000u);
}

// ---------------- graph build ----------------

__global__ void hist_kernel(const int* __restrict__ dst, int* __restrict__ deg, int E) {
    int i = blockIdx.x * blockDim.x + threadIdx.x;
    int st = gridDim.x * blockDim.x;
    for (; i < E; i += st) atomicAdd(&deg[dst[i]], 1);
}

__global__ void dinv_kernel(const int* __restrict__ deg, float* __restrict__ dinv, int n) {
    int i = blockIdx.x * blockDim.x + threadIdx.x;
    if (i < n) dinv[i] = rsqrtf((float)deg[i] + 1.0f);
}

__global__ __launch_bounds__(1024) void scan_kernel(const int* __restrict__ deg,
                                                    int* __restrict__ row_ptr, int n) {
    __shared__ int sums[1024];
    int t = threadIdx.x;
    int chunk = (n + 1023) >> 10;
    int s0 = t * chunk;
    int s1 = s0 + chunk; if (s1 > n) s1 = n;
    int s = 0;
    for (int i = s0; i < s1; ++i) s += deg[i] + 1;
    sums[t] = s;
    __syncthreads();
    for (int off = 1; off < 1024; off <<= 1) {
        int v = (t >= off) ? sums[t - off] : 0;
        __syncthreads();
        sums[t] += v;
        __syncthreads();
    }
    int run = (t == 0) ? 0 : sums[t - 1];
    for (int i = s0; i < s1; ++i) { row_ptr[i] = run; run += deg[i] + 1; }
    if (t == 0) row_ptr[n] = sums[1023];
}

__global__ void fill_kernel(const int* __restrict__ src, const int* __restrict__ dst,
                            const int* __restrict__ row_ptr, int* __restrict__ cursor,
                            const float* __restrict__ dinv,
                            int* __restrict__ csr_src, float* __restrict__ csr_norm,
                            int E, int n) {
    int i = blockIdx.x * blockDim.x + threadIdx.x;
    int st = gridDim.x * blockDim.x;
    int total = E + n;
    for (; i < total; i += st) {
        if (i < E) {
            int s = src[i], d = dst[i];
            int pos = row_ptr[d] + atomicAdd(&cursor[d], 1);
            csr_src[pos] = s;
            csr_norm[pos] = dinv[s] * dinv[d];
        } else {
            int v = i - E;
            int pos = row_ptr[v + 1] - 1;
            csr_src[pos] = v;
            csr_norm[pos] = dinv[v] * dinv[v];
        }
    }
}

// ---------------- prep: f32 -> bf16 conversions ----------------

__global__ void f2b8_kernel(const float* __restrict__ in, unsigned short* __restrict__ out,
                            int ngroups) {
    int i = blockIdx.x * blockDim.x + threadIdx.x;
    if (i >= ngroups) return;
    float4 a = reinterpret_cast<const float4*>(in)[(size_t)i * 2];
    float4 b = reinterpret_cast<const float4*>(in)[(size_t)i * 2 + 1];
    uint4 r;
    r.x = f2bf(a.x) | ((unsigned)f2bf(a.y) << 16);
    r.y = f2bf(a.z) | ((unsigned)f2bf(a.w) << 16);
    r.z = f2bf(b.x) | ((unsigned)f2bf(b.y) << 16);
    r.w = f2bf(b.z) | ((unsigned)f2bf(b.w) << 16);
    reinterpret_cast<uint4*>(out)[i] = r;
}

__global__ void wtrans_kernel(const float* __restrict__ W, unsigned short* __restrict__ Wt) {
    __shared__ float tile[16][17];
    int k = blockIdx.y * 16 + threadIdx.y;
    int n = blockIdx.x * 16 + threadIdx.x;
    tile[threadIdx.y][threadIdx.x] = W[(size_t)k * 256 + n];
    __syncthreads();
    int on = blockIdx.x * 16 + threadIdx.y;
    int ok = blockIdx.y * 16 + threadIdx.x;
    Wt[(size_t)on * 256 + ok] = f2bf(tile[threadIdx.x][threadIdx.y]);
}

// ---------------- bf16 MFMA GEMM with register double-buffer ----------------
__global__ __launch_bounds__(256) void gemm_bf16_kernel(
        const unsigned short* __restrict__ A, const unsigned short* __restrict__ Wt,
        unsigned short* __restrict__ C, int M) {
    __shared__ __align__(16) unsigned short As[128 * 40];
    __shared__ __align__(16) unsigned short Bs[128 * 40];
    const int t = threadIdx.x;
    const int l = t & 63;
    const int w = t >> 6;
    const int wr = w >> 1, wc = w & 1;
    const int row0 = blockIdx.x * 128;
    const int col0 = blockIdx.y * 128;

    f32x4 acc[4][4];
    #pragma unroll
    for (int m = 0; m < 4; m++)
        #pragma unroll
        for (int n = 0; n < 4; n++) acc[m][n] = (f32x4){0.f, 0.f, 0.f, 0.f};

    const int sr = t >> 2;
    const int sc = (t & 3) * 8;
    const int rl = l & 15;
    const int kb = (l >> 4) * 8;

    uint4 va[2], ub[2];
    #pragma unroll
    for (int p = 0; p < 2; p++) {
        int r = sr + p * 64;
        int gr = row0 + r;
        va[p] = (gr < M) ? *reinterpret_cast<const uint4*>(A + (size_t)gr * 256 + sc)
                         : make_uint4(0u, 0u, 0u, 0u);
        ub[p] = *reinterpret_cast<const uint4*>(Wt + (size_t)(col0 + r) * 256 + sc);
    }

    for (int k0 = 0; k0 < 256; k0 += 32) {
        #pragma unroll
        for (int p = 0; p < 2; p++) {
            int r = sr + p * 64;
            *reinterpret_cast<uint4*>(&As[r * 40 + sc]) = va[p];
            *reinterpret_cast<uint4*>(&Bs[r * 40 + sc]) = ub[p];
        }
        __syncthreads();
        if (k0 + 32 < 256) {
            #pragma unroll
            for (int p = 0; p < 2; p++) {
                int r = sr + p * 64;
                int gr = row0 + r;
                va[p] = (gr < M) ? *reinterpret_cast<const uint4*>(A + (size_t)gr * 256 + k0 + 32 + sc)
                                 : make_uint4(0u, 0u, 0u, 0u);
                ub[p] = *reinterpret_cast<const uint4*>(Wt + (size_t)(col0 + r) * 256 + k0 + 32 + sc);
            }
        }
        bf16x8 af[4], bfr[4];
        #pragma unroll
        for (int m = 0; m < 4; m++)
            af[m] = *reinterpret_cast<const bf16x8*>(&As[(wr * 64 + m * 16 + rl) * 40 + kb]);
        #pragma unroll
        for (int n = 0; n < 4; n++)
            bfr[n] = *reinterpret_cast<const bf16x8*>(&Bs[(wc * 64 + n * 16 + rl) * 40 + kb]);
        #pragma unroll
        for (int m = 0; m < 4; m++)
            #pragma unroll
            for (int n = 0; n < 4; n++)
                acc[m][n] = __builtin_amdgcn_mfma_f32_16x16x32_bf16(af[m], bfr[n], acc[m][n], 0, 0, 0);
        __syncthreads();
    }
    const int rh = l >> 4;
    #pragma unroll
    for (int m = 0; m < 4; m++) {
        #pragma unroll
        for (int n = 0; n < 4; n++) {
            #pragma unroll
            for (int j = 0; j < 4; j++) {
                int gr = row0 + wr * 64 + m * 16 + rh * 4 + j;
                int gc = col0 + wc * 64 + n * 16 + rl;
                if (gr < M) C[(size_t)gr * 256 + gc] = f2bf(acc[m][n][j]);
            }
        }
    }
}

// ---------------- GEMM: T3[M x 40] = Hb(bf16) @ W3(f32) ----------------
__global__ __launch_bounds__(256) void gemm40_kernel(const unsigned short* __restrict__ A,
                                                     const float* __restrict__ W,
                                                     float* __restrict__ C, int M) {
    __shared__ float Hs[128][65];
    __shared__ float Ws[64][40];
    const int t = threadIdx.x;
    const int tr = t & 127;
    const int tg = t >> 7;
    const int row0 = blockIdx.x * 128;
    float acc[20];
    #pragma unroll
    for (int j = 0; j < 20; j++) acc[j] = 0.f;

    const int hr = t >> 4;
    const int hc = (t & 15) << 2;

    for (int k0 = 0; k0 < 256; k0 += 64) {
        #pragma unroll
        for (int p = 0; p < 8; p++) {
            int r = hr + p * 16;
            int gr = row0 + r;
            uint2 u = make_uint2(0u, 0u);
            if (gr < M) u = *reinterpret_cast<const uint2*>(A + (size_t)gr * 256 + k0 + hc);
            Hs[r][hc] = bflo(u.x); Hs[r][hc + 1] = bfhi(u.x);
            Hs[r][hc + 2] = bflo(u.y); Hs[r][hc + 3] = bfhi(u.y);
        }
        for (int i = t; i < 64 * 40; i += 256) {
            int r = i / 40, c = i - r * 40;
            Ws[r][c] = W[(size_t)(k0 + r) * 40 + c];
        }
        __syncthreads();
        #pragma unroll 4
        for (int kk = 0; kk < 64; ++kk) {
            float a = Hs[tr][kk];
            float b[20];
            #pragma unroll
            for (int q = 0; q < 5; q++)
                *reinterpret_cast<float4*>(&b[q * 4]) =
                    *reinterpret_cast<float4*>(&Ws[kk][tg * 20 + q * 4]);
            #pragma unroll
            for (int j = 0; j < 20; j++) acc[j] = fmaf(a, b[j], acc[j]);
        }
        __syncthreads();
    }
    int gr = row0 + tr;
    if (gr < M) {
        #pragma unroll
        for (int q = 0; q < 5; q++) {
            float4 v = make_float4(acc[q * 4], acc[q * 4 + 1], acc[q * 4 + 2], acc[q * 4 + 3]);
            *reinterpret_cast<float4*>(C + (size_t)gr * 40 + tg * 20 + q * 4) = v;
        }
    }
}

// ---------------- aggregation (bf16), cooperative edge load + 4x MLP ----------------
__global__ __launch_bounds__(256) void aggb_kernel(const unsigned short* __restrict__ T,
        const int* __restrict__ row_ptr, const int* __restrict__ csr_src,
        const float* __restrict__ csr_norm, const float* __restrict__ bias,
        unsigned short* __restrict__ H, int n, int do_relu) {
    int wid = threadIdx.x >> 6, lane = threadIdx.x & 63;
    int node = blockIdx.x * 4 + wid;
    if (node >= n) return;
    int e0 = row_ptr[node], end = row_ptr[node + 1];
    float a0 = 0.f, a1 = 0.f, a2 = 0.f, a3 = 0.f;
    for (int base = e0; base < end; base += 64) {
        int cnt = min(64, end - base);
        int sv = 0; float wv = 0.f;
        if (lane < cnt) { sv = csr_src[base + lane]; wv = csr_norm[base + lane]; }
        int j = 0;
        for (; j + 3 < cnt; j += 4) {
            int s0 = __shfl(sv, j),     s1 = __shfl(sv, j + 1);
            int s2 = __shfl(sv, j + 2), s3 = __shfl(sv, j + 3);
            float w0 = __shfl(wv, j),     w1 = __shfl(wv, j + 1);
            float w2 = __shfl(wv, j + 2), w3 = __shfl(wv, j + 3);
            uint2 u0 = *reinterpret_cast<const uint2*>(T + (size_t)s0 * 256 + lane * 4);
            uint2 u1 = *reinterpret_cast<const uint2*>(T + (size_t)s1 * 256 + lane * 4);
            uint2 u2 = *reinterpret_cast<const uint2*>(T + (size_t)s2 * 256 + lane * 4);
            uint2 u3 = *reinterpret_cast<const uint2*>(T + (size_t)s3 * 256 + lane * 4);
            a0 = fmaf(w0, bflo(u0.x), a0); a1 = fmaf(w0, bfhi(u0.x), a1);
            a2 = fmaf(w0, bflo(u0.y), a2); a3 = fmaf(w0, bfhi(u0.y), a3);
            a0 = fmaf(w1, bflo(u1.x), a0); a1 = fmaf(w1, bfhi(u1.x), a1);
            a2 = fmaf(w1, bflo(u1.y), a2); a3 = fmaf(w1, bfhi(u1.y), a3);
            a0 = fmaf(w2, bflo(u2.x), a0); a1 = fmaf(w2, bfhi(u2.x), a1);
            a2 = fmaf(w2, bflo(u2.y), a2); a3 = fmaf(w2, bfhi(u2.y), a3);
            a0 = fmaf(w3, bflo(u3.x), a0); a1 = fmaf(w3, bfhi(u3.x), a1);
            a2 = fmaf(w3, bflo(u3.y), a2); a3 = fmaf(w3, bfhi(u3.y), a3);
        }
        for (; j < cnt; ++j) {
            int s0 = __shfl(sv, j);
            float w0 = __shfl(wv, j);
            uint2 u0 = *reinterpret_cast<const uint2*>(T + (size_t)s0 * 256 + lane * 4);
            a0 = fmaf(w0, bflo(u0.x), a0); a1 = fmaf(w0, bfhi(u0.x), a1);
            a2 = fmaf(w0, bflo(u0.y), a2); a3 = fmaf(w0, bfhi(u0.y), a3);
        }
    }
    float4 bb = reinterpret_cast<const float4*>(bias)[lane];
    a0 += bb.x; a1 += bb.y; a2 += bb.z; a3 += bb.w;
    if (do_relu) {
        a0 = fmaxf(a0, 0.f); a1 = fmaxf(a1, 0.f);
        a2 = fmaxf(a2, 0.f); a3 = fmaxf(a3, 0.f);
    }
    uint2 o;
    o.x = f2bf(a0) | ((unsigned)f2bf(a1) << 16);
    o.y = f2bf(a2) | ((unsigned)f2bf(a3) << 16);
    *reinterpret_cast<uint2*>(H + (size_t)node * 256 + lane * 4) = o;
}

// final layer: 40-ch aggregation + bias + log_softmax, cooperative + 4x MLP
__global__ __launch_bounds__(256) void agg40_kernel(const float* __restrict__ T3,
        const int* __restrict__ row_ptr, const int* __restrict__ csr_src,
        const float* __restrict__ csr_norm, const float* __restrict__ bias,
        float* __restrict__ Out, int n) {
    int wid = threadIdx.x >> 6, lane = threadIdx.x & 63;
    int node = blockIdx.x * 4 + wid;
    if (node >= n) return;
    bool act = lane < OC;
    int e0 = row_ptr[node], end = row_ptr[node + 1];
    float acc = 0.f;
    for (int base = e0; base < end; base += 64) {
        int cnt = min(64, end - base);
        int sv = 0; float wv = 0.f;
        if (lane < cnt) { sv = csr_src[base + lane]; wv = csr_norm[base + lane]; }
        int j = 0;
        for (; j + 3 < cnt; j += 4) {
            int s0 = __shfl(sv, j),     s1 = __shfl(sv, j + 1);
            int s2 = __shfl(sv, j + 2), s3 = __shfl(sv, j + 3);
            float w0 = __shfl(wv, j),     w1 = __shfl(wv, j + 1);
            float w2 = __shfl(wv, j + 2), w3 = __shfl(wv, j + 3);
            float v0 = act ? T3[(size_t)s0 * OC + lane] : 0.f;
            float v1 = act ? T3[(size_t)s1 * OC + lane] : 0.f;
            float v2 = act ? T3[(size_t)s2 * OC + lane] : 0.f;
            float v3 = act ? T3[(size_t)s3 * OC + lane] : 0.f;
            acc = fmaf(w0, v0, acc);
            acc = fmaf(w1, v1, acc);
            acc = fmaf(w2, v2, acc);
            acc = fmaf(w3, v3, acc);
        }
        for (; j < cnt; ++j) {
            int s0 = __shfl(sv, j);
            float w0 = __shfl(wv, j);
            float v0 = act ? T3[(size_t)s0 * OC + lane] : 0.f;
            acc = fmaf(w0, v0, acc);
        }
    }
    float bb = act ? bias[lane] : 0.f;
    float x = act ? (acc + bb) : -INFINITY;
    float m = x;
    #pragma unroll
    for (int off = 32; off; off >>= 1) m = fmaxf(m, __shfl_xor(m, off));
    float ex = act ? expf(x - m) : 0.f;
    float ssum = ex;
    #pragma unroll
    for (int off = 32; off; off >>= 1) ssum += __shfl_xor(ssum, off);
    if (act) Out[(size_t)node * OC + lane] = x - m - logf(ssum);
}

// ---------------- launch ----------------

extern "C" void kernel_launch(void* const* d_in, const int* in_sizes, int n_in,
                              void* d_out, int out_size, void* d_ws, size_t ws_size,
                              hipStream_t stream) {
    const float* x  = (const float*)d_in[0];
    const int* ei   = (const int*)d_in[1];
    const int* esrc = ei;
    const int* edst = ei + NE;
    const float* W1 = (const float*)d_in[2];
    const float* b1 = (const float*)d_in[3];
    const float* W2 = (const float*)d_in[4];
    const float* b2 = (const float*)d_in[5];
    const float* W3 = (const float*)d_in[6];
    const float* b3 = (const float*)d_in[7];
    float* out = (float*)d_out;

    char* p = (char*)d_ws;
    int* deg      = (int*)p;   p += 400000;
    int* cursor   = (int*)p;   p += 400000;
    int* row_ptr  = (int*)p;   p += 400128;
    float* dinv   = (float*)p; p += 400000;
    int* csr_src  = (int*)p;   p += (size_t)(NE + NN) * 4;
    float* csr_nm = (float*)p; p += (size_t)(NE + NN) * 4;
    unsigned short* Xb  = (unsigned short*)p; p += (size_t)NN * CH * 2;
    unsigned short* Wt1 = (unsigned short*)p; p += 256 * 256 * 2;
    unsigned short* Wt2 = (unsigned short*)p; p += 256 * 256 * 2;
    unsigned short* Tb  = (unsigned short*)p; p += (size_t)NN * CH * 2;
    unsigned short* Hb  = (unsigned short*)p; p += (size_t)NN * CH * 2;
    float* T3     = (float*)p; p += (size_t)NN * OC * 4;

    hipMemsetAsync(deg, 0, 800000, stream);

    hist_kernel<<<2048, 256, 0, stream>>>(edst, deg, NE);
    dinv_kernel<<<(NN + 255) / 256, 256, 0, stream>>>(deg, dinv, NN);
    scan_kernel<<<1, 1024, 0, stream>>>(deg, row_ptr, NN);
    fill_kernel<<<2048, 256, 0, stream>>>(esrc, edst, row_ptr, cursor, dinv,
                                          csr_src, csr_nm, NE, NN);

    f2b8_kernel<<<(NN * CH / 8 + 255) / 256, 256, 0, stream>>>(x, Xb, NN * CH / 8);
    {
        dim3 g(16, 16), b(16, 16);
        wtrans_kernel<<<g, b, 0, stream>>>(W1, Wt1);
        wtrans_kernel<<<g, b, 0, stream>>>(W2, Wt2);
    }

    dim3 gg((NN + 127) / 128, 2);
    gemm_bf16_kernel<<<gg, 256, 0, stream>>>(Xb, Wt1, Tb, NN);
    aggb_kernel<<<NN / 4, 256, 0, stream>>>(Tb, row_ptr, csr_src, csr_nm, b1, Hb, NN, 1);
    gemm_bf16_kernel<<<gg, 256, 0, stream>>>(Hb, Wt2, Tb, NN);
    aggb_kernel<<<NN / 4, 256, 0, stream>>>(Tb, row_ptr, csr_src, csr_nm, b2, Hb, NN, 1);
    gemm40_kernel<<<(NN + 127) / 128, 256, 0, stream>>>(Hb, W3, T3, NN);
    agg40_kernel<<<NN / 4, 256, 0, stream>>>(T3, row_ptr, csr_src, csr_nm, b3, out, NN);
}

// Round 5
// 855.758 us; speedup vs baseline: 1.7807x; 1.1769x over previous
//
#include <hip/hip_runtime.h>
#include <math.h>
#include <cstddef>

#define NN 100000
#define NE 1600000
#define CH 256
#define OC 40

typedef __attribute__((ext_vector_type(8))) short bf16x8;
typedef __attribute__((ext_vector_type(4))) float f32x4;

static __device__ __forceinline__ unsigned short f2bf(float f) {
    unsigned int u = __float_as_uint(f);
    unsigned int r = (u + 0x7FFFu + ((u >> 16) & 1u)) >> 16;
    return (unsigned short)r;
}
static __device__ __forceinline__ float bflo(unsigned int u) {
    return __uint_as_float(u << 16);
}
static __device__ __forceinline__ float bfhi(unsigned int u) {
    return __uint_as_float(u & 0xFFFF0000u);
}

// ---------------- graph build ----------------

__global__ void hist_kernel(const int* __restrict__ dst, int* __restrict__ deg, int E) {
    int i = blockIdx.x * blockDim.x + threadIdx.x;
    int st = gridDim.x * blockDim.x;
    for (; i < E; i += st) atomicAdd(&deg[dst[i]], 1);
}

__global__ void dinv_kernel(const int* __restrict__ deg, float* __restrict__ dinv, int n) {
    int i = blockIdx.x * blockDim.x + threadIdx.x;
    if (i < n) dinv[i] = rsqrtf((float)deg[i] + 1.0f);
}

// ---- hierarchical scan: row_ptr = exclusive_scan(deg+1), row_ptr[n] = total ----
__global__ __launch_bounds__(256) void scan1_kernel(const int* __restrict__ deg,
        int* __restrict__ row_ptr, int* __restrict__ bsum, int n) {
    __shared__ int s[256];
    int t = threadIdx.x;
    int i = blockIdx.x * 256 + t;
    int v = (i < n) ? deg[i] + 1 : 0;
    s[t] = v;
    __syncthreads();
    #pragma unroll
    for (int off = 1; off < 256; off <<= 1) {
        int u = (t >= off) ? s[t - off] : 0;
        __syncthreads();
        s[t] += u;
        __syncthreads();
    }
    if (i < n) row_ptr[i] = s[t] - v;          // exclusive local prefix
    if (t == 255) bsum[blockIdx.x] = s[255];   // block total
}

__global__ __launch_bounds__(512) void scan2_kernel(const int* __restrict__ bsum,
        int* __restrict__ boff, int* __restrict__ row_ptr, int nb, int n) {
    __shared__ int s[512];
    int t = threadIdx.x;
    int v = (t < nb) ? bsum[t] : 0;
    s[t] = v;
    __syncthreads();
    #pragma unroll
    for (int off = 1; off < 512; off <<= 1) {
        int u = (t >= off) ? s[t - off] : 0;
        __syncthreads();
        s[t] += u;
        __syncthreads();
    }
    if (t < nb) boff[t] = s[t] - v;            // exclusive block offset
    if (t == nb - 1) row_ptr[n] = s[t];        // grand total
}

__global__ __launch_bounds__(256) void scan3_kernel(int* __restrict__ row_ptr,
        const int* __restrict__ boff, int n) {
    int i = blockIdx.x * 256 + threadIdx.x;
    if (i < n) row_ptr[i] += boff[i >> 8];
}

__global__ void fill_kernel(const int* __restrict__ src, const int* __restrict__ dst,
                            const int* __restrict__ row_ptr, int* __restrict__ cursor,
                            const float* __restrict__ dinv,
                            int* __restrict__ csr_src, float* __restrict__ csr_norm,
                            int E, int n) {
    int i = blockIdx.x * blockDim.x + threadIdx.x;
    int st = gridDim.x * blockDim.x;
    int total = E + n;
    for (; i < total; i += st) {
        if (i < E) {
            int s = src[i], d = dst[i];
            int pos = row_ptr[d] + atomicAdd(&cursor[d], 1);
            csr_src[pos] = s;
            csr_norm[pos] = dinv[s] * dinv[d];
        } else {
            int v = i - E;
            int pos = row_ptr[v + 1] - 1;
            csr_src[pos] = v;
            csr_norm[pos] = dinv[v] * dinv[v];
        }
    }
}

// ---------------- prep: f32 -> bf16 conversions ----------------

__global__ void f2b8_kernel(const float* __restrict__ in, unsigned short* __restrict__ out,
                            int ngroups) {
    int i = blockIdx.x * blockDim.x + threadIdx.x;
    if (i >= ngroups) return;
    float4 a = reinterpret_cast<const float4*>(in)[(size_t)i * 2];
    float4 b = reinterpret_cast<const float4*>(in)[(size_t)i * 2 + 1];
    uint4 r;
    r.x = f2bf(a.x) | ((unsigned)f2bf(a.y) << 16);
    r.y = f2bf(a.z) | ((unsigned)f2bf(a.w) << 16);
    r.z = f2bf(b.x) | ((unsigned)f2bf(b.y) << 16);
    r.w = f2bf(b.z) | ((unsigned)f2bf(b.w) << 16);
    reinterpret_cast<uint4*>(out)[i] = r;
}

__global__ void wtrans_kernel(const float* __restrict__ W, unsigned short* __restrict__ Wt) {
    __shared__ float tile[16][17];
    int k = blockIdx.y * 16 + threadIdx.y;
    int n = blockIdx.x * 16 + threadIdx.x;
    tile[threadIdx.y][threadIdx.x] = W[(size_t)k * 256 + n];
    __syncthreads();
    int on = blockIdx.x * 16 + threadIdx.y;
    int ok = blockIdx.y * 16 + threadIdx.x;
    Wt[(size_t)on * 256 + ok] = f2bf(tile[threadIdx.x][threadIdx.y]);
}

// ---------------- bf16 MFMA GEMM with register double-buffer ----------------
__global__ __launch_bounds__(256) void gemm_bf16_kernel(
        const unsigned short* __restrict__ A, const unsigned short* __restrict__ Wt,
        unsigned short* __restrict__ C, int M) {
    __shared__ __align__(16) unsigned short As[128 * 40];
    __shared__ __align__(16) unsigned short Bs[128 * 40];
    const int t = threadIdx.x;
    const int l = t & 63;
    const int w = t >> 6;
    const int wr = w >> 1, wc = w & 1;
    const int row0 = blockIdx.x * 128;
    const int col0 = blockIdx.y * 128;

    f32x4 acc[4][4];
    #pragma unroll
    for (int m = 0; m < 4; m++)
        #pragma unroll
        for (int n = 0; n < 4; n++) acc[m][n] = (f32x4){0.f, 0.f, 0.f, 0.f};

    const int sr = t >> 2;
    const int sc = (t & 3) * 8;
    const int rl = l & 15;
    const int kb = (l >> 4) * 8;

    uint4 va[2], ub[2];
    #pragma unroll
    for (int p = 0; p < 2; p++) {
        int r = sr + p * 64;
        int gr = row0 + r;
        va[p] = (gr < M) ? *reinterpret_cast<const uint4*>(A + (size_t)gr * 256 + sc)
                         : make_uint4(0u, 0u, 0u, 0u);
        ub[p] = *reinterpret_cast<const uint4*>(Wt + (size_t)(col0 + r) * 256 + sc);
    }

    for (int k0 = 0; k0 < 256; k0 += 32) {
        #pragma unroll
        for (int p = 0; p < 2; p++) {
            int r = sr + p * 64;
            *reinterpret_cast<uint4*>(&As[r * 40 + sc]) = va[p];
            *reinterpret_cast<uint4*>(&Bs[r * 40 + sc]) = ub[p];
        }
        __syncthreads();
        if (k0 + 32 < 256) {
            #pragma unroll
            for (int p = 0; p < 2; p++) {
                int r = sr + p * 64;
                int gr = row0 + r;
                va[p] = (gr < M) ? *reinterpret_cast<const uint4*>(A + (size_t)gr * 256 + k0 + 32 + sc)
                                 : make_uint4(0u, 0u, 0u, 0u);
                ub[p] = *reinterpret_cast<const uint4*>(Wt + (size_t)(col0 + r) * 256 + k0 + 32 + sc);
            }
        }
        bf16x8 af[4], bfr[4];
        #pragma unroll
        for (int m = 0; m < 4; m++)
            af[m] = *reinterpret_cast<const bf16x8*>(&As[(wr * 64 + m * 16 + rl) * 40 + kb]);
        #pragma unroll
        for (int n = 0; n < 4; n++)
            bfr[n] = *reinterpret_cast<const bf16x8*>(&Bs[(wc * 64 + n * 16 + rl) * 40 + kb]);
        #pragma unroll
        for (int m = 0; m < 4; m++)
            #pragma unroll
            for (int n = 0; n < 4; n++)
                acc[m][n] = __builtin_amdgcn_mfma_f32_16x16x32_bf16(af[m], bfr[n], acc[m][n], 0, 0, 0);
        __syncthreads();
    }
    const int rh = l >> 4;
    #pragma unroll
    for (int m = 0; m < 4; m++) {
        #pragma unroll
        for (int n = 0; n < 4; n++) {
            #pragma unroll
            for (int j = 0; j < 4; j++) {
                int gr = row0 + wr * 64 + m * 16 + rh * 4 + j;
                int gc = col0 + wc * 64 + n * 16 + rl;
                if (gr < M) C[(size_t)gr * 256 + gc] = f2bf(acc[m][n][j]);
            }
        }
    }
}

// ---------------- GEMM: T3[M x 40] = Hb(bf16) @ W3(f32) ----------------
__global__ __launch_bounds__(256) void gemm40_kernel(const unsigned short* __restrict__ A,
                                                     const float* __restrict__ W,
                                                     float* __restrict__ C, int M) {
    __shared__ float Hs[128][65];
    __shared__ float Ws[64][40];
    const int t = threadIdx.x;
    const int tr = t & 127;
    const int tg = t >> 7;
    const int row0 = blockIdx.x * 128;
    float acc[20];
    #pragma unroll
    for (int j = 0; j < 20; j++) acc[j] = 0.f;

    const int hr = t >> 4;
    const int hc = (t & 15) << 2;

    for (int k0 = 0; k0 < 256; k0 += 64) {
        #pragma unroll
        for (int p = 0; p < 8; p++) {
            int r = hr + p * 16;
            int gr = row0 + r;
            uint2 u = make_uint2(0u, 0u);
            if (gr < M) u = *reinterpret_cast<const uint2*>(A + (size_t)gr * 256 + k0 + hc);
            Hs[r][hc] = bflo(u.x); Hs[r][hc + 1] = bfhi(u.x);
            Hs[r][hc + 2] = bflo(u.y); Hs[r][hc + 3] = bfhi(u.y);
        }
        for (int i = t; i < 64 * 40; i += 256) {
            int r = i / 40, c = i - r * 40;
            Ws[r][c] = W[(size_t)(k0 + r) * 40 + c];
        }
        __syncthreads();
        #pragma unroll 4
        for (int kk = 0; kk < 64; ++kk) {
            float a = Hs[tr][kk];
            float b[20];
            #pragma unroll
            for (int q = 0; q < 5; q++)
                *reinterpret_cast<float4*>(&b[q * 4]) =
                    *reinterpret_cast<float4*>(&Ws[kk][tg * 20 + q * 4]);
            #pragma unroll
            for (int j = 0; j < 20; j++) acc[j] = fmaf(a, b[j], acc[j]);
        }
        __syncthreads();
    }
    int gr = row0 + tr;
    if (gr < M) {
        #pragma unroll
        for (int q = 0; q < 5; q++) {
            float4 v = make_float4(acc[q * 4], acc[q * 4 + 1], acc[q * 4 + 2], acc[q * 4 + 3]);
            *reinterpret_cast<float4*>(C + (size_t)gr * 40 + tg * 20 + q * 4) = v;
        }
    }
}

// ---------------- aggregation (bf16), cooperative edge load + 4x MLP ----------------
__global__ __launch_bounds__(256) void aggb_kernel(const unsigned short* __restrict__ T,
        const int* __restrict__ row_ptr, const int* __restrict__ csr_src,
        const float* __restrict__ csr_norm, const float* __restrict__ bias,
        unsigned short* __restrict__ H, int n, int do_relu) {
    int wid = threadIdx.x >> 6, lane = threadIdx.x & 63;
    int node = blockIdx.x * 4 + wid;
    if (node >= n) return;
    int e0 = row_ptr[node], end = row_ptr[node + 1];
    float a0 = 0.f, a1 = 0.f, a2 = 0.f, a3 = 0.f;
    for (int base = e0; base < end; base += 64) {
        int cnt = min(64, end - base);
        int sv = 0; float wv = 0.f;
        if (lane < cnt) { sv = csr_src[base + lane]; wv = csr_norm[base + lane]; }
        int j = 0;
        for (; j + 3 < cnt; j += 4) {
            int s0 = __shfl(sv, j),     s1 = __shfl(sv, j + 1);
            int s2 = __shfl(sv, j + 2), s3 = __shfl(sv, j + 3);
            float w0 = __shfl(wv, j),     w1 = __shfl(wv, j + 1);
            float w2 = __shfl(wv, j + 2), w3 = __shfl(wv, j + 3);
            uint2 u0 = *reinterpret_cast<const uint2*>(T + (size_t)s0 * 256 + lane * 4);
            uint2 u1 = *reinterpret_cast<const uint2*>(T + (size_t)s1 * 256 + lane * 4);
            uint2 u2 = *reinterpret_cast<const uint2*>(T + (size_t)s2 * 256 + lane * 4);
            uint2 u3 = *reinterpret_cast<const uint2*>(T + (size_t)s3 * 256 + lane * 4);
            a0 = fmaf(w0, bflo(u0.x), a0); a1 = fmaf(w0, bfhi(u0.x), a1);
            a2 = fmaf(w0, bflo(u0.y), a2); a3 = fmaf(w0, bfhi(u0.y), a3);
            a0 = fmaf(w1, bflo(u1.x), a0); a1 = fmaf(w1, bfhi(u1.x), a1);
            a2 = fmaf(w1, bflo(u1.y), a2); a3 = fmaf(w1, bfhi(u1.y), a3);
            a0 = fmaf(w2, bflo(u2.x), a0); a1 = fmaf(w2, bfhi(u2.x), a1);
            a2 = fmaf(w2, bflo(u2.y), a2); a3 = fmaf(w2, bfhi(u2.y), a3);
            a0 = fmaf(w3, bflo(u3.x), a0); a1 = fmaf(w3, bfhi(u3.x), a1);
            a2 = fmaf(w3, bflo(u3.y), a2); a3 = fmaf(w3, bfhi(u3.y), a3);
        }
        for (; j < cnt; ++j) {
            int s0 = __shfl(sv, j);
            float w0 = __shfl(wv, j);
            uint2 u0 = *reinterpret_cast<const uint2*>(T + (size_t)s0 * 256 + lane * 4);
            a0 = fmaf(w0, bflo(u0.x), a0); a1 = fmaf(w0, bfhi(u0.x), a1);
            a2 = fmaf(w0, bflo(u0.y), a2); a3 = fmaf(w0, bfhi(u0.y), a3);
        }
    }
    float4 bb = reinterpret_cast<const float4*>(bias)[lane];
    a0 += bb.x; a1 += bb.y; a2 += bb.z; a3 += bb.w;
    if (do_relu) {
        a0 = fmaxf(a0, 0.f); a1 = fmaxf(a1, 0.f);
        a2 = fmaxf(a2, 0.f); a3 = fmaxf(a3, 0.f);
    }
    uint2 o;
    o.x = f2bf(a0) | ((unsigned)f2bf(a1) << 16);
    o.y = f2bf(a2) | ((unsigned)f2bf(a3) << 16);
    *reinterpret_cast<uint2*>(H + (size_t)node * 256 + lane * 4) = o;
}

// final layer: 40-ch aggregation + bias + log_softmax, cooperative + 4x MLP
__global__ __launch_bounds__(256) void agg40_kernel(const float* __restrict__ T3,
        const int* __restrict__ row_ptr, const int* __restrict__ csr_src,
        const float* __restrict__ csr_norm, const float* __restrict__ bias,
        float* __restrict__ Out, int n) {
    int wid = threadIdx.x >> 6, lane = threadIdx.x & 63;
    int node = blockIdx.x * 4 + wid;
    if (node >= n) return;
    bool act = lane < OC;
    int e0 = row_ptr[node], end = row_ptr[node + 1];
    float acc = 0.f;
    for (int base = e0; base < end; base += 64) {
        int cnt = min(64, end - base);
        int sv = 0; float wv = 0.f;
        if (lane < cnt) { sv = csr_src[base + lane]; wv = csr_norm[base + lane]; }
        int j = 0;
        for (; j + 3 < cnt; j += 4) {
            int s0 = __shfl(sv, j),     s1 = __shfl(sv, j + 1);
            int s2 = __shfl(sv, j + 2), s3 = __shfl(sv, j + 3);
            float w0 = __shfl(wv, j),     w1 = __shfl(wv, j + 1);
            float w2 = __shfl(wv, j + 2), w3 = __shfl(wv, j + 3);
            float v0 = act ? T3[(size_t)s0 * OC + lane] : 0.f;
            float v1 = act ? T3[(size_t)s1 * OC + lane] : 0.f;
            float v2 = act ? T3[(size_t)s2 * OC + lane] : 0.f;
            float v3 = act ? T3[(size_t)s3 * OC + lane] : 0.f;
            acc = fmaf(w0, v0, acc);
            acc = fmaf(w1, v1, acc);
            acc = fmaf(w2, v2, acc);
            acc = fmaf(w3, v3, acc);
        }
        for (; j < cnt; ++j) {
            int s0 = __shfl(sv, j);
            float w0 = __shfl(wv, j);
            float v0 = act ? T3[(size_t)s0 * OC + lane] : 0.f;
            acc = fmaf(w0, v0, acc);
        }
    }
    float bb = act ? bias[lane] : 0.f;
    float x = act ? (acc + bb) : -INFINITY;
    float m = x;
    #pragma unroll
    for (int off = 32; off; off >>= 1) m = fmaxf(m, __shfl_xor(m, off));
    float ex = act ? expf(x - m) : 0.f;
    float ssum = ex;
    #pragma unroll
    for (int off = 32; off; off >>= 1) ssum += __shfl_xor(ssum, off);
    if (act) Out[(size_t)node * OC + lane] = x - m - logf(ssum);
}

// ---------------- launch ----------------

extern "C" void kernel_launch(void* const* d_in, const int* in_sizes, int n_in,
                              void* d_out, int out_size, void* d_ws, size_t ws_size,
                              hipStream_t stream) {
    const float* x  = (const float*)d_in[0];
    const int* ei   = (const int*)d_in[1];
    const int* esrc = ei;
    const int* edst = ei + NE;
    const float* W1 = (const float*)d_in[2];
    const float* b1 = (const float*)d_in[3];
    const float* W2 = (const float*)d_in[4];
    const float* b2 = (const float*)d_in[5];
    const float* W3 = (const float*)d_in[6];
    const float* b3 = (const float*)d_in[7];
    float* out = (float*)d_out;

    char* p = (char*)d_ws;
    int* deg      = (int*)p;   p += 400000;
    int* cursor   = (int*)p;   p += 400000;
    int* row_ptr  = (int*)p;   p += 400128;
    float* dinv   = (float*)p; p += 400000;
    int* bsum     = (int*)p;   p += 2048;
    int* boff     = (int*)p;   p += 2048;
    int* csr_src  = (int*)p;   p += (size_t)(NE + NN) * 4;
    float* csr_nm = (float*)p; p += (size_t)(NE + NN) * 4;
    unsigned short* Xb  = (unsigned short*)p; p += (size_t)NN * CH * 2;
    unsigned short* Wt1 = (unsigned short*)p; p += 256 * 256 * 2;
    unsigned short* Wt2 = (unsigned short*)p; p += 256 * 256 * 2;
    unsigned short* Tb  = (unsigned short*)p; p += (size_t)NN * CH * 2;
    unsigned short* Hb  = (unsigned short*)p; p += (size_t)NN * CH * 2;
    float* T3     = (float*)p; p += (size_t)NN * OC * 4;

    hipMemsetAsync(deg, 0, 800000, stream);

    const int nb = (NN + 255) / 256;  // 391

    hist_kernel<<<2048, 256, 0, stream>>>(edst, deg, NE);
    dinv_kernel<<<(NN + 255) / 256, 256, 0, stream>>>(deg, dinv, NN);
    scan1_kernel<<<nb, 256, 0, stream>>>(deg, row_ptr, bsum, NN);
    scan2_kernel<<<1, 512, 0, stream>>>(bsum, boff, NN ? row_ptr : row_ptr, nb, NN);
    scan3_kernel<<<nb, 256, 0, stream>>>(row_ptr, boff, NN);
    fill_kernel<<<2048, 256, 0, stream>>>(esrc, edst, row_ptr, cursor, dinv,
                                          csr_src, csr_nm, NE, NN);

    f2b8_kernel<<<(NN * CH / 8 + 255) / 256, 256, 0, stream>>>(x, Xb, NN * CH / 8);
    {
        dim3 g(16, 16), b(16, 16);
        wtrans_kernel<<<g, b, 0, stream>>>(W1, Wt1);
        wtrans_kernel<<<g, b, 0, stream>>>(W2, Wt2);
    }

    dim3 gg((NN + 127) / 128, 2);
    gemm_bf16_kernel<<<gg, 256, 0, stream>>>(Xb, Wt1, Tb, NN);
    aggb_kernel<<<NN / 4, 256, 0, stream>>>(Tb, row_ptr, csr_src, csr_nm, b1, Hb, NN, 1);
    gemm_bf16_kernel<<<gg, 256, 0, stream>>>(Hb, Wt2, Tb, NN);
    aggb_kernel<<<NN / 4, 256, 0, stream>>>(Tb, row_ptr, csr_src, csr_nm, b2, Hb, NN, 1);
    gemm40_kernel<<<(NN + 127) / 128, 256, 0, stream>>>(Hb, W3, T3, NN);
    agg40_kernel<<<NN / 4, 256, 0, stream>>>(T3, row_ptr, csr_src, csr_nm, b3, out, NN);
}